// Round 1
// baseline (29729.642 us; speedup 1.0000x reference)
//
#include <hip/hip_runtime.h>

// LSTMClassification: B=64, T=512, IN=128, H=512, 2 layers + FC(512->1)
// Persistent-LSTM design: per layer, 64 workgroups; WG w owns h-columns
// [8w, 8w+8) => 32 gate rows {q*512 + 8w + c}. Weights live in LDS (bf16,
// XOR-swizzled). Per timestep each WG computes gates[64 x 32] via
// mfma_f32_16x16x32_bf16 (A = activations from global, B = weight slice from
// LDS), then the LSTM cell in fp32, publishes h (bf16) to a parity-double-
// buffered global state, and synchronizes via fence + atomic counters.

#define NWG 64
#define NB 64      // batch
#define NT 512     // seq len
#define NH 512     // hidden

typedef float f32x4 __attribute__((ext_vector_type(4)));
typedef __bf16 bf16x4 __attribute__((ext_vector_type(4)));
typedef __bf16 bf16x8 __attribute__((ext_vector_type(8)));

__global__ void prep_kernel(unsigned short* hs0, unsigned short* hs1, unsigned* cnt) {
    int i = blockIdx.x * blockDim.x + threadIdx.x;
    if (i < 2 * NB * NH) { hs0[i] = 0; hs1[i] = 0; }   // both parity h-state bufs, both layers
    if (i < 2 * NT) cnt[i] = 0;                        // step counters, both layers
}

template<int KIH, int IS_L0>
__launch_bounds__(512)
__global__ void lstm_layer_kernel(
    const float* __restrict__ W_ih, const float* __restrict__ W_hh,
    const float* __restrict__ b_ih, const float* __restrict__ b_hh,
    const float* __restrict__ x_f32,       // L0: x [NB][NT][KIH] fp32
    const __bf16* __restrict__ h_in_all,   // L1: h0_all [NT][NB][NH] bf16
    __bf16* __restrict__ h_out_all,        // L0: h0_all [NT][NB][NH]
    __bf16* __restrict__ hstate,           // [2][NB][NH] parity double buffer
    float* __restrict__ h_final,           // L1: [NB][NH] fp32
    unsigned* __restrict__ cnt)            // [NT]
{
    constexpr int KTOT = KIH + NH;
    constexpr int NCH_A = KIH / 32;        // input-contribution K-chunks
    constexpr int NCH_B = NH / 32;         // recurrent K-chunks
    constexpr int ROWB = KTOT * 2;         // LDS bytes per weight row

    __shared__ __align__(16) char Wl[32 * ROWB];   // L0: 40KB, L1: 64KB
    __shared__ float gbuf[64][36];                 // padded: conflict-free epilogue
    __shared__ float c_lds[64][8];                 // fp32 cell state (WG-private)

    const int tid = threadIdx.x;
    const int wg = blockIdx.x;
    const int hcol0 = wg * 8;

    // ---- stage weight slice into LDS (bf16, row-XOR swizzle) ----
    {
        constexpr int CPR = KTOT / 8;              // 16B chunks per row
        for (int cid = tid; cid < 32 * CPR; cid += 512) {
            const int r = cid / CPR;
            const int k0 = (cid - r * CPR) * 8;
            const int grow = (r >> 3) * NH + hcol0 + (r & 7);   // global gate row
            const float* src = (k0 < KIH) ? (W_ih + (size_t)grow * KIH + k0)
                                          : (W_hh + (size_t)grow * NH + (k0 - KIH));
            union { __bf16 h[8]; uint4 u; } tmp;
            #pragma unroll
            for (int j = 0; j < 8; ++j) tmp.h[j] = (__bf16)src[j];
            const unsigned off = (unsigned)(r * ROWB) +
                (((unsigned)(2 * k0)) ^ ((unsigned)((r & 7) << 4)));
            *(uint4*)(Wl + off) = tmp.u;
        }
    }

    // epilogue mapping: thread -> (batch eb, h-col ec); biases folded once
    const int eb = tid >> 3, ec = tid & 7;
    const int hcE = hcol0 + ec;
    const float bI = b_ih[hcE]          + b_hh[hcE];
    const float bF = b_ih[NH + hcE]     + b_hh[NH + hcE];
    const float bG = b_ih[2 * NH + hcE] + b_hh[2 * NH + hcE];
    const float bO = b_ih[3 * NH + hcE] + b_hh[3 * NH + hcE];
    c_lds[eb][ec] = 0.0f;
    __syncthreads();

    // MFMA mapping: 8 waves = 4 batch-tiles x 2 gate-tiles of 16x16
    const int lane = tid & 63;
    const int wid = tid >> 6;
    const int bt = (wid & 3) * 16;
    const int gt = (wid >> 2) * 16;
    const int arow = bt + (lane & 15);             // batch row (A)
    const int q4 = ((lane >> 4) & 3) * 4;          // k sub-offset per lane group
    const int brow = gt + (lane & 15);             // local gate row (B)
    const char* wrow = Wl + brow * ROWB;
    const unsigned bsz = (unsigned)((brow & 7) << 4);

    for (int t = 0; t < NT; ++t) {
        const __bf16* __restrict__ hprev = hstate + (size_t)(t & 1) * NB * NH;
        __bf16* __restrict__ hout = hstate + (size_t)((t + 1) & 1) * NB * NH;

        f32x4 acc = {0.f, 0.f, 0.f, 0.f};

        auto do_chunk = [&](int k0, bf16x4 alo, bf16x4 ahi) {
            const bf16x4 blo = *(const bf16x4*)(wrow + (((unsigned)(2 * (k0 + q4))) ^ bsz));
            const bf16x4 bhi = *(const bf16x4*)(wrow + (((unsigned)(2 * (k0 + 16 + q4))) ^ bsz));
            const bf16x8 av = __builtin_shufflevector(alo, ahi, 0, 1, 2, 3, 4, 5, 6, 7);
            const bf16x8 bv = __builtin_shufflevector(blo, bhi, 0, 1, 2, 3, 4, 5, 6, 7);
            acc = __builtin_amdgcn_mfma_f32_16x16x32_bf16(av, bv, acc, 0, 0, 0);
        };

        // phase A: input contribution (no dependence on h_{t-1}) -- hides the wait
        if constexpr (IS_L0 != 0) {
            const float* xb = x_f32 + ((size_t)arow * NT + t) * KIH;
            #pragma unroll
            for (int kk = 0; kk < NCH_A; ++kk) {
                const int k0 = kk * 32;
                const float4 lo = *(const float4*)(xb + k0 + q4);
                const float4 hi = *(const float4*)(xb + k0 + 16 + q4);
                const bf16x4 alo = {(__bf16)lo.x, (__bf16)lo.y, (__bf16)lo.z, (__bf16)lo.w};
                const bf16x4 ahi = {(__bf16)hi.x, (__bf16)hi.y, (__bf16)hi.z, (__bf16)hi.w};
                do_chunk(k0, alo, ahi);
            }
        } else {
            const __bf16* hb = h_in_all + ((size_t)t * NB + arow) * NH;
            #pragma unroll
            for (int kk = 0; kk < NCH_A; ++kk) {
                const int k0 = kk * 32;
                const bf16x4 alo = *(const bf16x4*)(hb + k0 + q4);
                const bf16x4 ahi = *(const bf16x4*)(hb + k0 + 16 + q4);
                do_chunk(k0, alo, ahi);
            }
        }

        // wait until all WGs published h_{t-1}
        if (t > 0) {
            if (tid == 0) {
                int guard = 0;
                while (__hip_atomic_load(&cnt[t - 1], __ATOMIC_RELAXED,
                                         __HIP_MEMORY_SCOPE_AGENT) < (unsigned)NWG) {
                    __builtin_amdgcn_s_sleep(2);
                    if (++guard > (1 << 20)) break;   // safety: never hard-hang
                }
            }
            __syncthreads();
            __threadfence();    // acquire: invalidate L1 so h_{t-1} reads are fresh
        }

        // phase B: recurrent contribution
        {
            const __bf16* hp = hprev + (size_t)arow * NH;
            #pragma unroll
            for (int kk = 0; kk < NCH_B; ++kk) {
                const int k0 = KIH + kk * 32;
                const int ak = kk * 32;
                const bf16x4 alo = *(const bf16x4*)(hp + ak + q4);
                const bf16x4 ahi = *(const bf16x4*)(hp + ak + 16 + q4);
                do_chunk(k0, alo, ahi);
            }
        }

        // scatter C tile (row = batch = (lane>>4)*4+i, col = gate = lane&15)
        #pragma unroll
        for (int i = 0; i < 4; ++i)
            gbuf[bt + ((lane >> 4) & 3) * 4 + i][gt + (lane & 15)] = acc[i];
        __syncthreads();

        // LSTM cell, fp32 (gate order i, f, g, o)
        {
            const float gi = gbuf[eb][ec]      + bI;
            const float gf = gbuf[eb][8 + ec]  + bF;
            const float gg = gbuf[eb][16 + ec] + bG;
            const float go = gbuf[eb][24 + ec] + bO;
            const float ii = 1.0f / (1.0f + __expf(-gi));
            const float ff = 1.0f / (1.0f + __expf(-gf));
            const float g2 = 2.0f / (1.0f + __expf(-2.0f * gg)) - 1.0f;   // tanh, saturating-safe
            const float oo = 1.0f / (1.0f + __expf(-go));
            const float cn = ff * c_lds[eb][ec] + ii * g2;
            const float th = 2.0f / (1.0f + __expf(-2.0f * cn)) - 1.0f;
            const float hn = oo * th;
            c_lds[eb][ec] = cn;
            const __bf16 hb = (__bf16)hn;
            hout[(size_t)eb * NH + hcol0 + ec] = hb;
            if constexpr (IS_L0 != 0) {
                h_out_all[((size_t)t * NB + eb) * NH + hcol0 + ec] = hb;
            } else {
                if (t == NT - 1) h_final[(size_t)eb * NH + hcol0 + ec] = hn;
            }
        }
        __threadfence();      // release: make h stores device-visible
        __syncthreads();
        if (tid == 0) atomicAdd(&cnt[t], 1u);
    }
}

__global__ void fc_kernel(const float* __restrict__ hfin,
                          const float* __restrict__ w_fc,
                          const float* __restrict__ b_fc,
                          float* __restrict__ out) {
    __shared__ float red[64][9];
    const int tid = threadIdx.x;
    const int b = tid >> 3, p = tid & 7;
    const int k0 = p * 64;
    float s = 0.f;
    #pragma unroll 8
    for (int k = 0; k < 64; ++k) s += hfin[(size_t)b * NH + k0 + k] * w_fc[k0 + k];
    red[b][p] = s;
    __syncthreads();
    if (p == 0) {
        float a = 0.f;
        #pragma unroll
        for (int j = 0; j < 8; ++j) a += red[b][j];
        out[b] = a + b_fc[0];
    }
}

extern "C" void kernel_launch(void* const* d_in, const int* in_sizes, int n_in,
                              void* d_out, int out_size, void* d_ws, size_t ws_size,
                              hipStream_t stream) {
    const float* x     = (const float*)d_in[0];
    const float* W_ih0 = (const float*)d_in[1];
    const float* W_hh0 = (const float*)d_in[2];
    const float* b_ih0 = (const float*)d_in[3];
    const float* b_hh0 = (const float*)d_in[4];
    const float* W_ih1 = (const float*)d_in[5];
    const float* W_hh1 = (const float*)d_in[6];
    const float* b_ih1 = (const float*)d_in[7];
    const float* b_hh1 = (const float*)d_in[8];
    const float* W_fc  = (const float*)d_in[9];
    const float* b_fc  = (const float*)d_in[10];

    // workspace layout (bytes); total ~33.95 MB
    char* ws = (char*)d_ws;
    __bf16*  h0_all = (__bf16*)(ws);                         // 512*64*512*2 = 33,554,432
    __bf16*  hs0    = (__bf16*)(ws + 33554432);              // 2*64*512*2  = 131,072
    __bf16*  hs1    = (__bf16*)(ws + 33554432 + 131072);     // 131,072
    float*   hfin   = (float*) (ws + 33554432 + 262144);     // 64*512*4    = 131,072
    unsigned* cnt0  = (unsigned*)(ws + 33554432 + 393216);   // 512 u32
    unsigned* cnt1  = cnt0 + NT;                             // 512 u32

    prep_kernel<<<dim3(256), dim3(256), 0, stream>>>(
        (unsigned short*)hs0, (unsigned short*)hs1, cnt0);

    lstm_layer_kernel<128, 1><<<dim3(NWG), dim3(512), 0, stream>>>(
        W_ih0, W_hh0, b_ih0, b_hh0, x, nullptr, h0_all, hs0, nullptr, cnt0);

    lstm_layer_kernel<512, 0><<<dim3(NWG), dim3(512), 0, stream>>>(
        W_ih1, W_hh1, b_ih1, b_hh1, nullptr, h0_all, nullptr, hs1, hfin, cnt1);

    fc_kernel<<<dim3(1), dim3(512), 0, stream>>>(hfin, W_fc, b_fc, (float*)d_out);
}

// Round 2
// 13088.913 us; speedup vs baseline: 2.2714x; 2.2714x over previous
//
#include <hip/hip_runtime.h>

// LSTMClassification: B=64, T=512, IN=128, H=512, 2 layers + FC(512->1)
// Persistent-LSTM: per layer, 64 WGs; WG w owns h-columns [8w,8w+8) => 32 gate
// rows. Weights in LDS (bf16, XOR-swizzled). Per step: gates[64x32] via
// mfma_f32_16x16x32_bf16, fp32 LSTM cell, h published through the coherence
// point with cache-BYPASSING relaxed atomics (sc0 sc1) -- NO threadfence, so
// the per-XCD L2s are never written back/invalidated and x/weights stay hot.

#define NWG 64
#define NB 64      // batch
#define NT 512     // seq len
#define NH 512     // hidden

typedef float f32x4 __attribute__((ext_vector_type(4)));
typedef __bf16 bf16x4 __attribute__((ext_vector_type(4)));
typedef __bf16 bf16x8 __attribute__((ext_vector_type(8)));

__device__ __forceinline__ bf16x4 ld8_bypass(const __bf16* p) {
    // relaxed SYSTEM-scope atomic load -> global_load_dwordx2 sc0 sc1
    // (bypasses L1 + non-coherent L2; served by Infinity Cache). No fence insts.
    unsigned long long v = __hip_atomic_load((unsigned long long*)p,
                                             __ATOMIC_RELAXED, __HIP_MEMORY_SCOPE_SYSTEM);
    bf16x4 r;
    __builtin_memcpy(&r, &v, 8);
    return r;
}

__global__ void prep_kernel(unsigned short* hs0, unsigned short* hs1, unsigned* cnt) {
    int i = blockIdx.x * blockDim.x + threadIdx.x;
    if (i < 2 * NB * NH) { hs0[i] = 0; hs1[i] = 0; }   // both parity bufs, both layers
    if (i < 2 * NT) cnt[i] = 0;                        // step counters, both layers
}

template<int KIH, int IS_L0>
__launch_bounds__(512)
__global__ void lstm_layer_kernel(
    const float* __restrict__ W_ih, const float* __restrict__ W_hh,
    const float* __restrict__ b_ih, const float* __restrict__ b_hh,
    const float* __restrict__ x_f32,       // L0: x [NB][NT][KIH] fp32
    const __bf16* __restrict__ h_in_all,   // L1: h0_all [NT][NB][NH] bf16
    __bf16* __restrict__ h_out_all,        // L0: h0_all [NT][NB][NH]
    __bf16* __restrict__ hstate,           // [2][NB][NH] parity double buffer
    float* __restrict__ h_final,           // L1: [NB][NH] fp32
    unsigned* __restrict__ cnt)            // [NT]
{
    constexpr int KTOT = KIH + NH;
    constexpr int NCH_A = KIH / 32;        // input-contribution K-chunks
    constexpr int NCH_B = NH / 32;         // recurrent K-chunks (= 16)
    constexpr int ROWB = KTOT * 2;         // LDS bytes per weight row

    __shared__ __align__(16) char Wl[32 * ROWB];    // L0: 40KB, L1: 64KB
    __shared__ float gbuf[64][36];                  // padded epilogue buffer
    __shared__ float c_lds[64][8];                  // fp32 cell state
    __shared__ unsigned short hstage[64][8];        // h packing stage (1KB)

    const int tid = threadIdx.x;
    const int wg = blockIdx.x;
    const int hcol0 = wg * 8;

    // ---- stage weight slice into LDS (bf16, row-XOR swizzle) ----
    {
        constexpr int CPR = KTOT / 8;              // 16B chunks per row
        for (int cid = tid; cid < 32 * CPR; cid += 512) {
            const int r = cid / CPR;
            const int k0 = (cid - r * CPR) * 8;
            const int grow = (r >> 3) * NH + hcol0 + (r & 7);   // global gate row
            const float* src = (k0 < KIH) ? (W_ih + (size_t)grow * KIH + k0)
                                          : (W_hh + (size_t)grow * NH + (k0 - KIH));
            union { __bf16 h[8]; uint4 u; } tmp;
            #pragma unroll
            for (int j = 0; j < 8; ++j) tmp.h[j] = (__bf16)src[j];
            const unsigned off = (unsigned)(r * ROWB) +
                (((unsigned)(2 * k0)) ^ ((unsigned)((r & 7) << 4)));
            *(uint4*)(Wl + off) = tmp.u;
        }
    }

    // epilogue mapping: thread -> (batch eb, h-col ec); biases folded once
    const int eb = tid >> 3, ec = tid & 7;
    const int hcE = hcol0 + ec;
    const float bI = b_ih[hcE]          + b_hh[hcE];
    const float bF = b_ih[NH + hcE]     + b_hh[NH + hcE];
    const float bG = b_ih[2 * NH + hcE] + b_hh[2 * NH + hcE];
    const float bO = b_ih[3 * NH + hcE] + b_hh[3 * NH + hcE];
    c_lds[eb][ec] = 0.0f;
    __syncthreads();

    // MFMA mapping: 8 waves = 4 batch-tiles x 2 gate-tiles of 16x16
    const int lane = tid & 63;
    const int wid = tid >> 6;
    const int bt = (wid & 3) * 16;
    const int gt = (wid >> 2) * 16;
    const int arow = bt + (lane & 15);             // batch row (A)
    const int q4 = ((lane >> 4) & 3) * 4;          // k sub-offset per lane group
    const int brow = gt + (lane & 15);             // local gate row (B)
    const char* wrow = Wl + brow * ROWB;
    const unsigned bsz = (unsigned)((brow & 7) << 4);

    for (int t = 0; t < NT; ++t) {
        const __bf16* __restrict__ hprev = hstate + (size_t)(t & 1) * NB * NH;
        __bf16* __restrict__ hout = hstate + (size_t)((t + 1) & 1) * NB * NH;

        f32x4 acc = {0.f, 0.f, 0.f, 0.f};

        auto do_chunk = [&](int k0, bf16x4 alo, bf16x4 ahi) {
            const bf16x4 blo = *(const bf16x4*)(wrow + (((unsigned)(2 * (k0 + q4))) ^ bsz));
            const bf16x4 bhi = *(const bf16x4*)(wrow + (((unsigned)(2 * (k0 + 16 + q4))) ^ bsz));
            const bf16x8 av = __builtin_shufflevector(alo, ahi, 0, 1, 2, 3, 4, 5, 6, 7);
            const bf16x8 bv = __builtin_shufflevector(blo, bhi, 0, 1, 2, 3, 4, 5, 6, 7);
            acc = __builtin_amdgcn_mfma_f32_16x16x32_bf16(av, bv, acc, 0, 0, 0);
        };

        // phase A: input contribution (independent of h_{t-1}) -- hides wait skew
        if constexpr (IS_L0 != 0) {
            const float* xb = x_f32 + ((size_t)arow * NT + t) * KIH;
            #pragma unroll
            for (int kk = 0; kk < NCH_A; ++kk) {
                const int k0 = kk * 32;
                const float4 lo = *(const float4*)(xb + k0 + q4);
                const float4 hi = *(const float4*)(xb + k0 + 16 + q4);
                const bf16x4 alo = {(__bf16)lo.x, (__bf16)lo.y, (__bf16)lo.z, (__bf16)lo.w};
                const bf16x4 ahi = {(__bf16)hi.x, (__bf16)hi.y, (__bf16)hi.z, (__bf16)hi.w};
                do_chunk(k0, alo, ahi);
            }
        } else {
            const __bf16* hb = h_in_all + ((size_t)t * NB + arow) * NH;
            #pragma unroll
            for (int kk = 0; kk < NCH_A; ++kk) {
                const int k0 = kk * 32;
                const bf16x4 alo = *(const bf16x4*)(hb + k0 + q4);
                const bf16x4 ahi = *(const bf16x4*)(hb + k0 + 16 + q4);
                do_chunk(k0, alo, ahi);
            }
        }

        // wait until all WGs published h_{t-1} (flag via bypass load; no fence)
        if (t > 0) {
            if (tid == 0) {
                int guard = 0;
                while (__hip_atomic_load(&cnt[t - 1], __ATOMIC_RELAXED,
                                         __HIP_MEMORY_SCOPE_SYSTEM) < (unsigned)NWG) {
                    __builtin_amdgcn_s_sleep(1);
                    if (++guard > (1 << 20)) break;   // safety: never hard-hang
                }
            }
            __syncthreads();
        }

        // phase B: preload ALL h_{t-1} fragments (32 bypass loads in flight),
        // then run the MFMA chain. Batching avoids per-chunk latency serialization.
        {
            const __bf16* hp = hprev + (size_t)arow * NH;
            bf16x4 alo[NCH_B], ahi[NCH_B];
            #pragma unroll
            for (int kk = 0; kk < NCH_B; ++kk) {
                alo[kk] = ld8_bypass(hp + kk * 32 + q4);
                ahi[kk] = ld8_bypass(hp + kk * 32 + 16 + q4);
            }
            #pragma unroll
            for (int kk = 0; kk < NCH_B; ++kk)
                do_chunk(KIH + kk * 32, alo[kk], ahi[kk]);
        }

        // scatter C tile (row = batch = (lane>>4)*4+i, col = gate = lane&15)
        #pragma unroll
        for (int i = 0; i < 4; ++i)
            gbuf[bt + ((lane >> 4) & 3) * 4 + i][gt + (lane & 15)] = acc[i];
        __syncthreads();

        // LSTM cell, fp32 (gate order i, f, g, o)
        {
            const float gi = gbuf[eb][ec]      + bI;
            const float gf = gbuf[eb][8 + ec]  + bF;
            const float gg = gbuf[eb][16 + ec] + bG;
            const float go = gbuf[eb][24 + ec] + bO;
            const float ii = 1.0f / (1.0f + __expf(-gi));
            const float ff = 1.0f / (1.0f + __expf(-gf));
            const float g2 = 2.0f / (1.0f + __expf(-2.0f * gg)) - 1.0f;   // tanh
            const float oo = 1.0f / (1.0f + __expf(-go));
            const float cn = ff * c_lds[eb][ec] + ii * g2;
            const float th = 2.0f / (1.0f + __expf(-2.0f * cn)) - 1.0f;
            const float hn = oo * th;
            c_lds[eb][ec] = cn;
            const __bf16 hb = (__bf16)hn;
            unsigned short ub;
            __builtin_memcpy(&ub, &hb, 2);
            hstage[eb][ec] = ub;                       // stage for packed publish
            if constexpr (IS_L0 != 0) {
                h_out_all[((size_t)t * NB + eb) * NH + hcol0 + ec] = hb;  // cached store
            } else {
                if (t == NT - 1) h_final[(size_t)eb * NH + hcol0 + ec] = hn;
            }
        }
        __syncthreads();

        // publish h slice: 128 threads x 8B bypass stores (write-through to L3)
        if (tid < 128) {
            const int b = tid >> 1, half = tid & 1;
            unsigned long long v;
            __builtin_memcpy(&v, &hstage[b][half * 4], 8);
            __hip_atomic_store((unsigned long long*)(hout + (size_t)b * NH + hcol0 + half * 4),
                               v, __ATOMIC_RELAXED, __HIP_MEMORY_SCOPE_SYSTEM);
        }
        asm volatile("s_waitcnt vmcnt(0)" ::: "memory");   // drain own stores to L3
        __syncthreads();                                   // all threads' stores drained
        if (tid == 0)
            __hip_atomic_fetch_add(&cnt[t], 1u, __ATOMIC_RELAXED, __HIP_MEMORY_SCOPE_SYSTEM);
    }
}

__global__ void fc_kernel(const float* __restrict__ hfin,
                          const float* __restrict__ w_fc,
                          const float* __restrict__ b_fc,
                          float* __restrict__ out) {
    __shared__ float red[64][9];
    const int tid = threadIdx.x;
    const int b = tid >> 3, p = tid & 7;
    const int k0 = p * 64;
    float s = 0.f;
    #pragma unroll 8
    for (int k = 0; k < 64; ++k) s += hfin[(size_t)b * NH + k0 + k] * w_fc[k0 + k];
    red[b][p] = s;
    __syncthreads();
    if (p == 0) {
        float a = 0.f;
        #pragma unroll
        for (int j = 0; j < 8; ++j) a += red[b][j];
        out[b] = a + b_fc[0];
    }
}

extern "C" void kernel_launch(void* const* d_in, const int* in_sizes, int n_in,
                              void* d_out, int out_size, void* d_ws, size_t ws_size,
                              hipStream_t stream) {
    const float* x     = (const float*)d_in[0];
    const float* W_ih0 = (const float*)d_in[1];
    const float* W_hh0 = (const float*)d_in[2];
    const float* b_ih0 = (const float*)d_in[3];
    const float* b_hh0 = (const float*)d_in[4];
    const float* W_ih1 = (const float*)d_in[5];
    const float* W_hh1 = (const float*)d_in[6];
    const float* b_ih1 = (const float*)d_in[7];
    const float* b_hh1 = (const float*)d_in[8];
    const float* W_fc  = (const float*)d_in[9];
    const float* b_fc  = (const float*)d_in[10];

    // workspace layout (bytes); total ~33.95 MB
    char* ws = (char*)d_ws;
    __bf16*  h0_all = (__bf16*)(ws);                         // 512*64*512*2 = 33,554,432
    __bf16*  hs0    = (__bf16*)(ws + 33554432);              // 2*64*512*2  = 131,072
    __bf16*  hs1    = (__bf16*)(ws + 33554432 + 131072);     // 131,072
    float*   hfin   = (float*) (ws + 33554432 + 262144);     // 64*512*4    = 131,072
    unsigned* cnt0  = (unsigned*)(ws + 33554432 + 393216);   // 512 u32
    unsigned* cnt1  = cnt0 + NT;                             // 512 u32

    prep_kernel<<<dim3(256), dim3(256), 0, stream>>>(
        (unsigned short*)hs0, (unsigned short*)hs1, cnt0);

    lstm_layer_kernel<128, 1><<<dim3(NWG), dim3(512), 0, stream>>>(
        W_ih0, W_hh0, b_ih0, b_hh0, x, nullptr, h0_all, hs0, nullptr, cnt0);

    lstm_layer_kernel<512, 0><<<dim3(NWG), dim3(512), 0, stream>>>(
        W_ih1, W_hh1, b_ih1, b_hh1, nullptr, h0_all, nullptr, hs1, hfin, cnt1);

    fc_kernel<<<dim3(1), dim3(512), 0, stream>>>(hfin, W_fc, b_fc, (float*)d_out);
}

// Round 3
// 8699.206 us; speedup vs baseline: 3.4175x; 1.5046x over previous
//
#include <hip/hip_runtime.h>

// LSTMClassification: B=64, T=512, IN=128, H=512, 2 layers + FC(512->1)
// Fused persistent-LSTM: ONE kernel, 128 WGs (0-63 = layer0, 64-127 = layer1),
// pipelined with 1-step skew. WG owns h-columns [8w,8w+8) => 32 gate rows in
// LDS (bf16, XOR-swizzled). Per step: gates[64x32] via mfma_f32_16x16x32_bf16
// with register-preloaded A fragments (4 independent acc chains), fp32 cell,
// h published via cache-bypassing AGENT-scope stores (sc flags; no fences,
// no L2 writeback/invalidate). Sync = per-WG flag words + one wave-wide poll
// (single coalesced load + __all) -- no contended atomic RMW.

#define NWG 64
#define NB 64      // batch
#define NT 512     // seq len
#define NH 512     // hidden

typedef float f32x4 __attribute__((ext_vector_type(4)));
typedef __bf16 bf16x4 __attribute__((ext_vector_type(4)));
typedef __bf16 bf16x8 __attribute__((ext_vector_type(8)));

__device__ __forceinline__ bf16x4 ld8_bypass(const __bf16* p) {
    unsigned long long v = __hip_atomic_load((const unsigned long long*)p,
                                             __ATOMIC_RELAXED, __HIP_MEMORY_SCOPE_AGENT);
    bf16x4 r; __builtin_memcpy(&r, &v, 8); return r;
}

__device__ __forceinline__ void st8_bypass(__bf16* p, unsigned long long v) {
    __hip_atomic_store((unsigned long long*)p, v, __ATOMIC_RELAXED, __HIP_MEMORY_SCOPE_AGENT);
}

// One full wave polls 64 per-WG flags (lane l watches flags[l]) until all >= target.
__device__ __forceinline__ void wait_flags(const unsigned* flags, unsigned target, int lane) {
    int guard = 0;
    for (;;) {
        unsigned f = __hip_atomic_load((unsigned*)&flags[lane],
                                       __ATOMIC_RELAXED, __HIP_MEMORY_SCOPE_AGENT);
        if (__all((int)(f >= target))) break;
        __builtin_amdgcn_s_sleep(1);
        if (++guard > (1 << 18)) break;   // safety: never hard-hang
    }
}

__global__ void prep_kernel(unsigned short* hs0, unsigned short* hs1, unsigned* flags) {
    int i = blockIdx.x * blockDim.x + threadIdx.x;
    if (i < 2 * NB * NH) { hs0[i] = 0; hs1[i] = 0; }   // both parity bufs, both layers
    if (i < 2 * NWG) flags[i] = 0;                     // flags0[64] ++ flags1[64]
}

template<int KIH, int IS_L0>
__device__ __forceinline__ void layer_body(
    char* Wl, float (*gbuf)[36], float (*c_lds)[8], unsigned short (*hstage)[8],
    int wg,
    const float* __restrict__ W_ih, const float* __restrict__ W_hh,
    const float* __restrict__ b_ih, const float* __restrict__ b_hh,
    const float* __restrict__ x_f32,       // L0: x [NB][NT][KIH] fp32
    const __bf16* __restrict__ h_in_all,   // L1: h0_all [NT][NB][NH] bf16 (bypass)
    __bf16* __restrict__ h_out_all,        // L0: h0_all [NT][NB][NH] (bypass)
    __bf16* __restrict__ hstate,           // [2][NB][NH] parity double buffer
    float* __restrict__ h_final,           // L1: [NB][NH] fp32
    unsigned* __restrict__ flags_self,     // [NWG] this layer's step flags
    const unsigned* __restrict__ flags_dep)// [NWG] producer layer's flags (L1 only)
{
    constexpr int KTOT = KIH + NH;
    constexpr int NCH_A = KIH / 32;
    constexpr int NCH_B = NH / 32;         // 16
    constexpr int ROWB = KTOT * 2;

    const int tid = threadIdx.x;
    const int hcol0 = wg * 8;

    // ---- stage weight slice into LDS (bf16, row-XOR swizzle) ----
    {
        constexpr int CPR = KTOT / 8;
        for (int cid = tid; cid < 32 * CPR; cid += 512) {
            const int r = cid / CPR;
            const int k0 = (cid - r * CPR) * 8;
            const int grow = (r >> 3) * NH + hcol0 + (r & 7);
            const float* src = (k0 < KIH) ? (W_ih + (size_t)grow * KIH + k0)
                                          : (W_hh + (size_t)grow * NH + (k0 - KIH));
            union { __bf16 h[8]; uint4 u; } tmp;
            #pragma unroll
            for (int j = 0; j < 8; ++j) tmp.h[j] = (__bf16)src[j];
            const unsigned off = (unsigned)(r * ROWB) +
                (((unsigned)(2 * k0)) ^ ((unsigned)((r & 7) << 4)));
            *(uint4*)(Wl + off) = tmp.u;
        }
    }

    // epilogue mapping + folded biases
    const int eb = tid >> 3, ec = tid & 7;
    const int hcE = hcol0 + ec;
    const float bI = b_ih[hcE]          + b_hh[hcE];
    const float bF = b_ih[NH + hcE]     + b_hh[NH + hcE];
    const float bG = b_ih[2 * NH + hcE] + b_hh[2 * NH + hcE];
    const float bO = b_ih[3 * NH + hcE] + b_hh[3 * NH + hcE];
    c_lds[eb][ec] = 0.0f;
    __syncthreads();

    // MFMA mapping: 8 waves = 4 batch-tiles x 2 gate-tiles of 16x16
    const int lane = tid & 63;
    const int wid = tid >> 6;
    const int bt = (wid & 3) * 16;
    const int gt = (wid >> 2) * 16;
    const int arow = bt + (lane & 15);
    const int q4 = ((lane >> 4) & 3) * 4;
    const int brow = gt + (lane & 15);
    const char* wrow = Wl + brow * ROWB;
    const unsigned bsz = (unsigned)((brow & 7) << 4);

    auto wfrag = [&](int k0) -> bf16x8 {
        const bf16x4 blo = *(const bf16x4*)(wrow + (((unsigned)(2 * (k0 + q4))) ^ bsz));
        const bf16x4 bhi = *(const bf16x4*)(wrow + (((unsigned)(2 * (k0 + 16 + q4))) ^ bsz));
        return __builtin_shufflevector(blo, bhi, 0, 1, 2, 3, 4, 5, 6, 7);
    };

    for (int t = 0; t < NT; ++t) {
        const __bf16* __restrict__ hprev = hstate + (size_t)(t & 1) * NB * NH;
        __bf16* __restrict__ hout = hstate + (size_t)((t + 1) & 1) * NB * NH;

        f32x4 accA0 = {0.f,0.f,0.f,0.f}, accA1 = {0.f,0.f,0.f,0.f};
        f32x4 accB0 = {0.f,0.f,0.f,0.f}, accB1 = {0.f,0.f,0.f,0.f};

        if constexpr (IS_L0 != 0) {
            // phase A from x (cached, no dependency) BEFORE the wait
            const float* xb = x_f32 + ((size_t)arow * NT + t) * KIH;
            bf16x8 av[NCH_A];
            #pragma unroll
            for (int kk = 0; kk < NCH_A; ++kk) {
                const float4 lo = *(const float4*)(xb + kk * 32 + q4);
                const float4 hi = *(const float4*)(xb + kk * 32 + 16 + q4);
                const bf16x4 alo = {(__bf16)lo.x, (__bf16)lo.y, (__bf16)lo.z, (__bf16)lo.w};
                const bf16x4 ahi = {(__bf16)hi.x, (__bf16)hi.y, (__bf16)hi.z, (__bf16)hi.w};
                av[kk] = __builtin_shufflevector(alo, ahi, 0, 1, 2, 3, 4, 5, 6, 7);
            }
            #pragma unroll
            for (int kk = 0; kk < NCH_A; ++kk) {
                f32x4& a = (kk & 1) ? accA1 : accA0;
                a = __builtin_amdgcn_mfma_f32_16x16x32_bf16(av[kk], wfrag(kk * 32), a, 0, 0, 0);
            }
            if (t > 0 && wid == 0) wait_flags(flags_self, (unsigned)t, lane);
            __syncthreads();
        } else {
            // L1: wave0 waits for producer step t complete; wave1 for own recurrence
            if (wid == 0) wait_flags(flags_dep, (unsigned)(t + 1), lane);
            if (wid == 1 && t > 0) wait_flags(flags_self, (unsigned)t, lane);
            __syncthreads();
        }

        // ---- preload ALL remaining A-fragments into registers (in-flight) ----
        bf16x4 aBlo[NCH_B], aBhi[NCH_B];
        {
            const __bf16* hp = hprev + (size_t)arow * NH;
            #pragma unroll
            for (int kk = 0; kk < NCH_B; ++kk) {
                aBlo[kk] = ld8_bypass(hp + kk * 32 + q4);
                aBhi[kk] = ld8_bypass(hp + kk * 32 + 16 + q4);
            }
        }
        if constexpr (IS_L0 == 0) {
            bf16x4 aAlo[NCH_A], aAhi[NCH_A];
            const __bf16* hb = h_in_all + ((size_t)t * NB + arow) * NH;
            #pragma unroll
            for (int kk = 0; kk < NCH_A; ++kk) {
                aAlo[kk] = ld8_bypass(hb + kk * 32 + q4);
                aAhi[kk] = ld8_bypass(hb + kk * 32 + 16 + q4);
            }
            #pragma unroll
            for (int kk = 0; kk < NCH_A; ++kk) {
                f32x4& a = (kk & 1) ? accA1 : accA0;
                const bf16x8 av = __builtin_shufflevector(aAlo[kk], aAhi[kk], 0,1,2,3,4,5,6,7);
                a = __builtin_amdgcn_mfma_f32_16x16x32_bf16(av, wfrag(kk * 32), a, 0, 0, 0);
            }
        }
        #pragma unroll
        for (int kk = 0; kk < NCH_B; ++kk) {
            f32x4& a = (kk & 1) ? accB1 : accB0;
            const bf16x8 av = __builtin_shufflevector(aBlo[kk], aBhi[kk], 0,1,2,3,4,5,6,7);
            a = __builtin_amdgcn_mfma_f32_16x16x32_bf16(av, wfrag(KIH + kk * 32), a, 0, 0, 0);
        }

        const f32x4 acc = (accA0 + accA1) + (accB0 + accB1);

        // scatter C tile (row = batch = (lane>>4)*4+i, col = gate = lane&15)
        #pragma unroll
        for (int i = 0; i < 4; ++i)
            gbuf[bt + ((lane >> 4) & 3) * 4 + i][gt + (lane & 15)] = acc[i];
        __syncthreads();

        // LSTM cell, fp32 (gate order i, f, g, o)
        {
            const float gi = gbuf[eb][ec]      + bI;
            const float gf = gbuf[eb][8 + ec]  + bF;
            const float gg = gbuf[eb][16 + ec] + bG;
            const float go = gbuf[eb][24 + ec] + bO;
            const float ii = 1.0f / (1.0f + __expf(-gi));
            const float ff = 1.0f / (1.0f + __expf(-gf));
            const float g2 = 2.0f / (1.0f + __expf(-2.0f * gg)) - 1.0f;   // tanh
            const float oo = 1.0f / (1.0f + __expf(-go));
            const float cn = ff * c_lds[eb][ec] + ii * g2;
            const float th = 2.0f / (1.0f + __expf(-2.0f * cn)) - 1.0f;
            const float hn = oo * th;
            c_lds[eb][ec] = cn;
            const __bf16 hb = (__bf16)hn;
            unsigned short ub;
            __builtin_memcpy(&ub, &hb, 2);
            hstage[eb][ec] = ub;
            if constexpr (IS_L0 == 0) {
                if (t == NT - 1) h_final[(size_t)eb * NH + hcol0 + ec] = hn;
            }
        }
        __syncthreads();

        // publish h slice: 128 threads x 8B bypass stores
        if (tid < 128) {
            const int b = tid >> 1, half = tid & 1;
            unsigned long long v;
            __builtin_memcpy(&v, &hstage[b][half * 4], 8);
            st8_bypass(hout + (size_t)b * NH + hcol0 + half * 4, v);
            if constexpr (IS_L0 != 0)
                st8_bypass(h_out_all + ((size_t)t * NB + b) * NH + hcol0 + half * 4, v);
        }
        asm volatile("s_waitcnt vmcnt(0)" ::: "memory");   // drain own stores
        __syncthreads();                                   // all waves drained
        if (tid == 0)
            __hip_atomic_store(&flags_self[wg], (unsigned)(t + 1),
                               __ATOMIC_RELAXED, __HIP_MEMORY_SCOPE_AGENT);
    }
}

__launch_bounds__(512, 2)
__global__ void lstm_fused_kernel(
    const float* W_ih0, const float* W_hh0, const float* b_ih0, const float* b_hh0,
    const float* W_ih1, const float* W_hh1, const float* b_ih1, const float* b_hh1,
    const float* x, __bf16* h0_all, __bf16* hs0, __bf16* hs1,
    float* hfin, unsigned* flags0, unsigned* flags1)
{
    __shared__ __align__(16) char Wl[32 * 2048];    // max(40KB, 64KB)
    __shared__ float gbuf[64][36];
    __shared__ float c_lds[64][8];
    __shared__ unsigned short hstage[64][8];

    if (blockIdx.x < NWG) {
        layer_body<128, 1>(Wl, gbuf, c_lds, hstage, blockIdx.x,
                           W_ih0, W_hh0, b_ih0, b_hh0,
                           x, nullptr, h0_all, hs0, nullptr, flags0, nullptr);
    } else {
        layer_body<512, 0>(Wl, gbuf, c_lds, hstage, blockIdx.x - NWG,
                           W_ih1, W_hh1, b_ih1, b_hh1,
                           nullptr, h0_all, nullptr, hs1, hfin, flags1, flags0);
    }
}

__global__ void fc_kernel(const float* __restrict__ hfin,
                          const float* __restrict__ w_fc,
                          const float* __restrict__ b_fc,
                          float* __restrict__ out) {
    __shared__ float red[64][9];
    const int tid = threadIdx.x;
    const int b = tid >> 3, p = tid & 7;
    const int k0 = p * 64;
    float s = 0.f;
    #pragma unroll 8
    for (int k = 0; k < 64; ++k) s += hfin[(size_t)b * NH + k0 + k] * w_fc[k0 + k];
    red[b][p] = s;
    __syncthreads();
    if (p == 0) {
        float a = 0.f;
        #pragma unroll
        for (int j = 0; j < 8; ++j) a += red[b][j];
        out[b] = a + b_fc[0];
    }
}

extern "C" void kernel_launch(void* const* d_in, const int* in_sizes, int n_in,
                              void* d_out, int out_size, void* d_ws, size_t ws_size,
                              hipStream_t stream) {
    const float* x     = (const float*)d_in[0];
    const float* W_ih0 = (const float*)d_in[1];
    const float* W_hh0 = (const float*)d_in[2];
    const float* b_ih0 = (const float*)d_in[3];
    const float* b_hh0 = (const float*)d_in[4];
    const float* W_ih1 = (const float*)d_in[5];
    const float* W_hh1 = (const float*)d_in[6];
    const float* b_ih1 = (const float*)d_in[7];
    const float* b_hh1 = (const float*)d_in[8];
    const float* W_fc  = (const float*)d_in[9];
    const float* b_fc  = (const float*)d_in[10];

    // workspace layout (bytes); total ~33.95 MB
    char* ws = (char*)d_ws;
    __bf16*  h0_all = (__bf16*)(ws);                         // 512*64*512*2 = 33,554,432
    __bf16*  hs0    = (__bf16*)(ws + 33554432);              // 2*64*512*2  = 131,072
    __bf16*  hs1    = (__bf16*)(ws + 33554432 + 131072);     // 131,072
    float*   hfin   = (float*) (ws + 33554432 + 262144);     // 64*512*4    = 131,072
    unsigned* flags0 = (unsigned*)(ws + 33554432 + 393216);  // 64 u32
    unsigned* flags1 = flags0 + NWG;                         // 64 u32

    prep_kernel<<<dim3(256), dim3(256), 0, stream>>>(
        (unsigned short*)hs0, (unsigned short*)hs1, flags0);

    lstm_fused_kernel<<<dim3(2 * NWG), dim3(512), 0, stream>>>(
        W_ih0, W_hh0, b_ih0, b_hh0, W_ih1, W_hh1, b_ih1, b_hh1,
        x, h0_all, hs0, hs1, hfin, flags0, flags1);

    fc_kernel<<<dim3(1), dim3(512), 0, stream>>>(hfin, W_fc, b_fc, (float*)d_out);
}

// Round 4
// 3117.346 us; speedup vs baseline: 9.5368x; 2.7906x over previous
//
#include <hip/hip_runtime.h>

// LSTMClassification: B=64, T=512, IN=128, H=512, 2 layers + FC(512->1)
// Fused persistent-LSTM: 128 WGs (0-63 = layer0, 64-127 = layer1), 1-step skew.
// WG w owns h-columns [8w,8w+8) => 32 gate rows in LDS (bf16, XOR-swizzled).
// h exchange through MALL via cache-bypassing AGENT-scope ops in a
// WG-BLOCK-MAJOR layout: hbuf[parity][wg][b][8] so producers write exclusive
// contiguous 1KB blocks and consumers read contiguous 256B runs (coalesced
// bypass transactions -- the round-3 bottleneck was 8B/1KB-strided bypass
// loads costing a full fabric transaction each). Flags padded to 64B stride.

#define NWG 64
#define NB 64      // batch
#define NT 512     // seq len
#define NH 512     // hidden
#define FPAD 16    // flag padding (u32s) = 64B stride

typedef float f32x4 __attribute__((ext_vector_type(4)));
typedef __bf16 bf16x4 __attribute__((ext_vector_type(4)));
typedef __bf16 bf16x8 __attribute__((ext_vector_type(8)));

__device__ __forceinline__ bf16x4 ld8_bypass(const __bf16* p) {
    unsigned long long v = __hip_atomic_load((const unsigned long long*)p,
                                             __ATOMIC_RELAXED, __HIP_MEMORY_SCOPE_AGENT);
    bf16x4 r; __builtin_memcpy(&r, &v, 8); return r;
}

__device__ __forceinline__ void st8_bypass(__bf16* p, unsigned long long v) {
    __hip_atomic_store((unsigned long long*)p, v, __ATOMIC_RELAXED, __HIP_MEMORY_SCOPE_AGENT);
}

// One full wave polls 64 per-WG flags (lane l watches flags[l*FPAD]) until all >= target.
__device__ __forceinline__ void wait_flags(const unsigned* flags, unsigned target, int lane) {
    int guard = 0;
    for (;;) {
        unsigned f = __hip_atomic_load((unsigned*)&flags[lane * FPAD],
                                       __ATOMIC_RELAXED, __HIP_MEMORY_SCOPE_AGENT);
        if (__all((int)(f >= target))) break;
        if (++guard > (1 << 17)) break;   // safety: never hard-hang
    }
}

__global__ void prep_kernel(unsigned short* hs0, unsigned short* hs1, unsigned* flags) {
    int i = blockIdx.x * blockDim.x + threadIdx.x;
    if (i < 2 * NWG * NB * 8) { hs0[i] = 0; hs1[i] = 0; }   // both parity block-bufs
    if (i < 2 * NWG * FPAD) flags[i] = 0;                   // padded flags, both layers
}

template<int KIH, int IS_L0>
__device__ __forceinline__ void layer_body(
    char* Wl, float (*gbuf)[36], float (*c_lds)[8], unsigned short (*hstage)[8],
    int wg,
    const float* __restrict__ W_ih, const float* __restrict__ W_hh,
    const float* __restrict__ b_ih, const float* __restrict__ b_hh,
    const float* __restrict__ x_f32,       // L0: x [NB][NT][KIH] fp32 (cached)
    const __bf16* __restrict__ h_in_all,   // L1: h0_all [NT][NWG][NB][8] (bypass)
    __bf16* __restrict__ h_out_all,        // L0: h0_all [NT][NWG][NB][8] (bypass)
    __bf16* __restrict__ hbuf,             // [2][NWG][NB][8] parity double buffer
    float* __restrict__ h_final,           // L1: [NB][NH] fp32
    unsigned* __restrict__ flags_self,     // [NWG*FPAD] this layer's step flags
    const unsigned* __restrict__ flags_dep)// [NWG*FPAD] producer layer's flags
{
    constexpr int KTOT = KIH + NH;
    constexpr int NCH_A = KIH / 32;
    constexpr int NCH_B = NH / 32;         // 16
    constexpr int ROWB = KTOT * 2;
    constexpr int BLK = NB * 8;            // elements per WG block (512)

    const int tid = threadIdx.x;
    const int hcol0 = wg * 8;

    // ---- stage weight slice into LDS (bf16, row-XOR swizzle) ----
    {
        constexpr int CPR = KTOT / 8;
        for (int cid = tid; cid < 32 * CPR; cid += 512) {
            const int r = cid / CPR;
            const int k0 = (cid - r * CPR) * 8;
            const int grow = (r >> 3) * NH + hcol0 + (r & 7);
            const float* src = (k0 < KIH) ? (W_ih + (size_t)grow * KIH + k0)
                                          : (W_hh + (size_t)grow * NH + (k0 - KIH));
            union { __bf16 h[8]; uint4 u; } tmp;
            #pragma unroll
            for (int j = 0; j < 8; ++j) tmp.h[j] = (__bf16)src[j];
            const unsigned off = (unsigned)(r * ROWB) +
                (((unsigned)(2 * k0)) ^ ((unsigned)((r & 7) << 4)));
            *(uint4*)(Wl + off) = tmp.u;
        }
    }

    // epilogue mapping + folded biases
    const int eb = tid >> 3, ec = tid & 7;
    const int hcE = hcol0 + ec;
    const float bI = b_ih[hcE]          + b_hh[hcE];
    const float bF = b_ih[NH + hcE]     + b_hh[NH + hcE];
    const float bG = b_ih[2 * NH + hcE] + b_hh[2 * NH + hcE];
    const float bO = b_ih[3 * NH + hcE] + b_hh[3 * NH + hcE];
    c_lds[eb][ec] = 0.0f;
    __syncthreads();

    // MFMA mapping: 8 waves = 4 batch-tiles x 2 gate-tiles of 16x16
    const int lane = tid & 63;
    const int wid = tid >> 6;
    const int bt = (wid & 3) * 16;
    const int gt = (wid >> 2) * 16;
    const int arow = bt + (lane & 15);
    const int q4 = ((lane >> 4) & 3) * 4;
    const int brow = gt + (lane & 15);
    const char* wrow = Wl + brow * ROWB;
    const unsigned bsz = (unsigned)((brow & 7) << 4);

    // block-layout A-fragment offsets: col = 32*kk + (q4>>3)*8 + (q4&4) + j
    const int aoff = arow * 8 + (q4 & 4);      // within-block element offset
    const int bsub = (q4 >> 3);                // sub-block select (0/1)

    auto wfrag = [&](int k0) -> bf16x8 {
        const bf16x4 blo = *(const bf16x4*)(wrow + (((unsigned)(2 * (k0 + q4))) ^ bsz));
        const bf16x4 bhi = *(const bf16x4*)(wrow + (((unsigned)(2 * (k0 + 16 + q4))) ^ bsz));
        return __builtin_shufflevector(blo, bhi, 0, 1, 2, 3, 4, 5, 6, 7);
    };

    for (int t = 0; t < NT; ++t) {
        const __bf16* __restrict__ hprev = hbuf + (size_t)(t & 1) * NWG * BLK;
        __bf16* __restrict__ hout = hbuf + (size_t)((t + 1) & 1) * NWG * BLK;

        f32x4 accA0 = {0.f,0.f,0.f,0.f}, accA1 = {0.f,0.f,0.f,0.f};
        f32x4 accB0 = {0.f,0.f,0.f,0.f}, accB1 = {0.f,0.f,0.f,0.f};

        if constexpr (IS_L0 != 0) {
            // phase A from x (cached, no dependency) BEFORE the wait
            const float* xb = x_f32 + ((size_t)arow * NT + t) * KIH;
            bf16x8 av[NCH_A];
            #pragma unroll
            for (int kk = 0; kk < NCH_A; ++kk) {
                const float4 lo = *(const float4*)(xb + kk * 32 + q4);
                const float4 hi = *(const float4*)(xb + kk * 32 + 16 + q4);
                const bf16x4 alo = {(__bf16)lo.x, (__bf16)lo.y, (__bf16)lo.z, (__bf16)lo.w};
                const bf16x4 ahi = {(__bf16)hi.x, (__bf16)hi.y, (__bf16)hi.z, (__bf16)hi.w};
                av[kk] = __builtin_shufflevector(alo, ahi, 0, 1, 2, 3, 4, 5, 6, 7);
            }
            #pragma unroll
            for (int kk = 0; kk < NCH_A; ++kk) {
                f32x4& a = (kk & 1) ? accA1 : accA0;
                a = __builtin_amdgcn_mfma_f32_16x16x32_bf16(av[kk], wfrag(kk * 32), a, 0, 0, 0);
            }
            if (t > 0 && wid == 0) wait_flags(flags_self, (unsigned)t, lane);
            __syncthreads();
        } else {
            // L1: wave0 waits for producer step t; wave1 for own recurrence t-1
            if (wid == 0) wait_flags(flags_dep, (unsigned)(t + 1), lane);
            if (wid == 1 && t > 0) wait_flags(flags_self, (unsigned)t, lane);
            __syncthreads();
        }

        // ---- preload A-fragments (block layout, coalesced bypass loads) ----
        bf16x4 aBlo[NCH_B], aBhi[NCH_B];
        #pragma unroll
        for (int kk = 0; kk < NCH_B; ++kk) {
            const __bf16* base = hprev + (4 * kk + bsub) * BLK + aoff;
            aBlo[kk] = ld8_bypass(base);
            aBhi[kk] = ld8_bypass(base + 2 * BLK);
        }
        if constexpr (IS_L0 == 0) {
            const __bf16* hA = h_in_all + (size_t)t * NWG * BLK;
            bf16x4 aAlo[NCH_A], aAhi[NCH_A];
            #pragma unroll
            for (int kk = 0; kk < NCH_A; ++kk) {
                const __bf16* base = hA + (4 * kk + bsub) * BLK + aoff;
                aAlo[kk] = ld8_bypass(base);
                aAhi[kk] = ld8_bypass(base + 2 * BLK);
            }
            #pragma unroll
            for (int kk = 0; kk < NCH_A; ++kk) {
                f32x4& a = (kk & 1) ? accA1 : accA0;
                const bf16x8 av = __builtin_shufflevector(aAlo[kk], aAhi[kk], 0,1,2,3,4,5,6,7);
                a = __builtin_amdgcn_mfma_f32_16x16x32_bf16(av, wfrag(kk * 32), a, 0, 0, 0);
            }
        }
        #pragma unroll
        for (int kk = 0; kk < NCH_B; ++kk) {
            f32x4& a = (kk & 1) ? accB1 : accB0;
            const bf16x8 av = __builtin_shufflevector(aBlo[kk], aBhi[kk], 0,1,2,3,4,5,6,7);
            a = __builtin_amdgcn_mfma_f32_16x16x32_bf16(av, wfrag(KIH + kk * 32), a, 0, 0, 0);
        }

        const f32x4 acc = (accA0 + accA1) + (accB0 + accB1);

        // scatter C tile (row = batch = (lane>>4)*4+i, col = gate = lane&15)
        #pragma unroll
        for (int i = 0; i < 4; ++i)
            gbuf[bt + ((lane >> 4) & 3) * 4 + i][gt + (lane & 15)] = acc[i];
        __syncthreads();

        // LSTM cell, fp32 (gate order i, f, g, o)
        {
            const float gi = gbuf[eb][ec]      + bI;
            const float gf = gbuf[eb][8 + ec]  + bF;
            const float gg = gbuf[eb][16 + ec] + bG;
            const float go = gbuf[eb][24 + ec] + bO;
            const float ii = 1.0f / (1.0f + __expf(-gi));
            const float ff = 1.0f / (1.0f + __expf(-gf));
            const float g2 = 2.0f / (1.0f + __expf(-2.0f * gg)) - 1.0f;   // tanh
            const float oo = 1.0f / (1.0f + __expf(-go));
            const float cn = ff * c_lds[eb][ec] + ii * g2;
            const float th = 2.0f / (1.0f + __expf(-2.0f * cn)) - 1.0f;
            const float hn = oo * th;
            c_lds[eb][ec] = cn;
            const __bf16 hb = (__bf16)hn;
            unsigned short ub;
            __builtin_memcpy(&ub, &hb, 2);
            hstage[eb][ec] = ub;
            if constexpr (IS_L0 == 0) {
                if (t == NT - 1) h_final[(size_t)eb * NH + hcol0 + ec] = hn;
            }
        }
        __syncthreads();

        // publish this WG's contiguous 1KB block: 128 threads x 8B bypass stores
        if (tid < 128) {
            unsigned long long v;
            __builtin_memcpy(&v, &hstage[tid >> 1][(tid & 1) * 4], 8);
            st8_bypass(hout + (size_t)wg * BLK + tid * 4, v);
            if constexpr (IS_L0 != 0)
                st8_bypass(h_out_all + ((size_t)t * NWG + wg) * BLK + tid * 4, v);
        }
        asm volatile("s_waitcnt vmcnt(0)" ::: "memory");   // drain own stores
        __syncthreads();                                   // all waves drained
        if (tid == 0)
            __hip_atomic_store(&flags_self[wg * FPAD], (unsigned)(t + 1),
                               __ATOMIC_RELAXED, __HIP_MEMORY_SCOPE_AGENT);
    }
}

__launch_bounds__(512, 2)
__global__ void lstm_fused_kernel(
    const float* W_ih0, const float* W_hh0, const float* b_ih0, const float* b_hh0,
    const float* W_ih1, const float* W_hh1, const float* b_ih1, const float* b_hh1,
    const float* x, __bf16* h0_all, __bf16* hs0, __bf16* hs1,
    float* hfin, unsigned* flags0, unsigned* flags1)
{
    __shared__ __align__(16) char Wl[32 * 2048];    // max(40KB, 64KB)
    __shared__ float gbuf[64][36];
    __shared__ float c_lds[64][8];
    __shared__ unsigned short hstage[64][8];

    if (blockIdx.x < NWG) {
        layer_body<128, 1>(Wl, gbuf, c_lds, hstage, blockIdx.x,
                           W_ih0, W_hh0, b_ih0, b_hh0,
                           x, nullptr, h0_all, hs0, nullptr, flags0, nullptr);
    } else {
        layer_body<512, 0>(Wl, gbuf, c_lds, hstage, blockIdx.x - NWG,
                           W_ih1, W_hh1, b_ih1, b_hh1,
                           nullptr, h0_all, nullptr, hs1, hfin, flags1, flags0);
    }
}

__global__ void fc_kernel(const float* __restrict__ hfin,
                          const float* __restrict__ w_fc,
                          const float* __restrict__ b_fc,
                          float* __restrict__ out) {
    __shared__ float red[64][9];
    const int tid = threadIdx.x;
    const int b = tid >> 3, p = tid & 7;
    const int k0 = p * 64;
    float s = 0.f;
    #pragma unroll 8
    for (int k = 0; k < 64; ++k) s += hfin[(size_t)b * NH + k0 + k] * w_fc[k0 + k];
    red[b][p] = s;
    __syncthreads();
    if (p == 0) {
        float a = 0.f;
        #pragma unroll
        for (int j = 0; j < 8; ++j) a += red[b][j];
        out[b] = a + b_fc[0];
    }
}

extern "C" void kernel_launch(void* const* d_in, const int* in_sizes, int n_in,
                              void* d_out, int out_size, void* d_ws, size_t ws_size,
                              hipStream_t stream) {
    const float* x     = (const float*)d_in[0];
    const float* W_ih0 = (const float*)d_in[1];
    const float* W_hh0 = (const float*)d_in[2];
    const float* b_ih0 = (const float*)d_in[3];
    const float* b_hh0 = (const float*)d_in[4];
    const float* W_ih1 = (const float*)d_in[5];
    const float* W_hh1 = (const float*)d_in[6];
    const float* b_ih1 = (const float*)d_in[7];
    const float* b_hh1 = (const float*)d_in[8];
    const float* W_fc  = (const float*)d_in[9];
    const float* b_fc  = (const float*)d_in[10];

    // workspace layout (bytes); total ~34 MB
    char* ws = (char*)d_ws;
    __bf16*  h0_all = (__bf16*)(ws);                         // 512*64*64*8*2 = 33,554,432
    __bf16*  hs0    = (__bf16*)(ws + 33554432);              // 2*64*64*8*2 = 131,072
    __bf16*  hs1    = (__bf16*)(ws + 33554432 + 131072);     // 131,072
    float*   hfin   = (float*) (ws + 33554432 + 262144);     // 64*512*4 = 131,072
    unsigned* flags0 = (unsigned*)(ws + 33554432 + 393216);  // 64*16 u32 = 4KB
    unsigned* flags1 = flags0 + NWG * FPAD;                  // 4KB

    prep_kernel<<<dim3(256), dim3(256), 0, stream>>>(
        (unsigned short*)hs0, (unsigned short*)hs1, flags0);

    lstm_fused_kernel<<<dim3(2 * NWG), dim3(512), 0, stream>>>(
        W_ih0, W_hh0, b_ih0, b_hh0, W_ih1, W_hh1, b_ih1, b_hh1,
        x, h0_all, hs0, hs1, hfin, flags0, flags1);

    fc_kernel<<<dim3(1), dim3(512), 0, stream>>>(hfin, W_fc, b_fc, (float*)d_out);
}